// Round 7
// baseline (127.512 us; speedup 1.0000x reference)
//
#include <hip/hip_runtime.h>
#include <math.h>

#define DD 2048
#define DTC 0.01f
#define NSTEPS 30

typedef float floatx4 __attribute__((ext_vector_type(4)));

__device__ __forceinline__ void lorenz_deriv(float x, float y, float z,
                                             float sigma, float rho, float beta,
                                             float& dx, float& dy, float& dz) {
    dx = sigma * (y - x);
    dy = x * (rho - z) - y;
    dz = x * y - beta * z;
}

__device__ __forceinline__ float fast_tanh(float p) {
    float e = __expf(2.0f * p);
    return 1.0f - __fdividef(2.0f, e + 1.0f);
}

// K_A: state0 = x @ W_in^T + b_in. 256 threads cover 8 rows: wave w handles
// rows {2w,2w+1} (one per 32-lane half); lane&31 owns 64 consecutive cols.
// No LDS, no barriers; 5-step intra-half shfl reduce.
__global__ __launch_bounds__(256) void kA_state0(
    const float* __restrict__ x, const float* __restrict__ W_in,
    const float* __restrict__ b_in, float* __restrict__ state0) {
    const int tid = threadIdx.x;
    const int lane = tid & 63;
    const int half = lane >> 5;
    const int wv = tid >> 6;
    const int row = blockIdx.x * 8 + wv * 2 + half;
    const int c0 = (lane & 31) * 64;

    const float* xp  = x + (size_t)row * DD + c0;
    const float* w0p = W_in + 0 * DD + c0;
    const float* w1p = W_in + 1 * DD + c0;
    const float* w2p = W_in + 2 * DD + c0;

    floatx4 a0 = {0.f,0.f,0.f,0.f}, a1 = a0, a2 = a0;
#pragma unroll
    for (int i = 0; i < 16; ++i) {
        const floatx4 xv = *reinterpret_cast<const floatx4*>(xp + 4 * i);
        a0 += xv * *reinterpret_cast<const floatx4*>(w0p + 4 * i);
        a1 += xv * *reinterpret_cast<const floatx4*>(w1p + 4 * i);
        a2 += xv * *reinterpret_cast<const floatx4*>(w2p + 4 * i);
    }
    float s0 = a0.x + a0.y + a0.z + a0.w;
    float s1 = a1.x + a1.y + a1.z + a1.w;
    float s2 = a2.x + a2.y + a2.z + a2.w;
#pragma unroll
    for (int off = 16; off > 0; off >>= 1) {
        s0 += __shfl_xor(s0, off, 64);
        s1 += __shfl_xor(s1, off, 64);
        s2 += __shfl_xor(s2, off, 64);
    }
    if ((lane & 31) == 0) {
        float* sp = state0 + (size_t)row * 3;
        sp[0] = s0 + b_in[0];
        sp[1] = s1 + b_in[1];
        sp[2] = s2 + b_in[2];
    }
}

// K_B: one thread per row, all 64 lanes integrate concurrently (packed waves).
__global__ __launch_bounds__(256) void kB_integrate(
    const float* __restrict__ state0, const float* __restrict__ lorenz,
    float* __restrict__ feats) {
    const int row = blockIdx.x * 256 + threadIdx.x;
    const float sigma = fmaxf(fabsf(lorenz[0]), 0.1f);
    const float rho   = fmaxf(fabsf(lorenz[1]), 0.1f);
    const float beta  = fmaxf(fabsf(lorenz[2]), 0.1f);

    float sx = state0[(size_t)row * 3 + 0];
    float sy = state0[(size_t)row * 3 + 1];
    float sz = state0[(size_t)row * 3 + 2];
    const float ix = sx, iy = sy, iz = sz;
    float sux = sx, suy = sy, suz = sz;
    float sqx = sx * sx, sqy = sy * sy, sqz = sz * sz;
    float mnx = sx, mny = sy, mnz = sz;
    float mxx = sx, mxy = sy, mxz = sz;
#pragma unroll 1
    for (int t = 0; t < NSTEPS; ++t) {
        float k1x, k1y, k1z, k2x, k2y, k2z, k3x, k3y, k3z, k4x, k4y, k4z;
        float ax, ay, az;
        lorenz_deriv(sx, sy, sz, sigma, rho, beta, k1x, k1y, k1z);
        ax = sx + 0.5f * DTC * k1x; ay = sy + 0.5f * DTC * k1y; az = sz + 0.5f * DTC * k1z;
        lorenz_deriv(ax, ay, az, sigma, rho, beta, k2x, k2y, k2z);
        ax = sx + 0.5f * DTC * k2x; ay = sy + 0.5f * DTC * k2y; az = sz + 0.5f * DTC * k2z;
        lorenz_deriv(ax, ay, az, sigma, rho, beta, k3x, k3y, k3z);
        ax = sx + DTC * k3x; ay = sy + DTC * k3y; az = sz + DTC * k3z;
        lorenz_deriv(ax, ay, az, sigma, rho, beta, k4x, k4y, k4z);
        sx += (DTC / 6.0f) * (k1x + 2.0f * k2x + 2.0f * k3x + k4x);
        sy += (DTC / 6.0f) * (k1y + 2.0f * k2y + 2.0f * k3y + k4y);
        sz += (DTC / 6.0f) * (k1z + 2.0f * k2z + 2.0f * k3z + k4z);
        sux += sx; suy += sy; suz += sz;
        sqx += sx * sx; sqy += sy * sy; sqz += sz * sz;
        mnx = fminf(mnx, sx); mny = fminf(mny, sy); mnz = fminf(mnz, sz);
        mxx = fmaxf(mxx, sx); mxy = fmaxf(mxy, sy); mxz = fmaxf(mxz, sz);
    }
    const float inv31 = 1.0f / 31.0f;
    const float inv30 = 1.0f / 30.0f;
    const float mex = sux * inv31, mey = suy * inv31, mez = suz * inv31;
    const float vax = fmaxf((sqx - sux * mex) * inv30, 0.0f);
    const float vay = fmaxf((sqy - suy * mey) * inv30, 0.0f);
    const float vaz = fmaxf((sqz - suz * mez) * inv30, 0.0f);
    float* f = feats + (size_t)row * 18;
    f[0]  = ix;  f[1]  = iy;  f[2]  = iz;
    f[3]  = sx;  f[4]  = sy;  f[5]  = sz;
    f[6]  = mex; f[7]  = mey; f[8]  = mez;
    f[9]  = sqrtf(vax); f[10] = sqrtf(vay); f[11] = sqrtf(vaz);
    f[12] = mnx; f[13] = mny; f[14] = mnz;
    f[15] = mxx; f[16] = mxy; f[17] = mxz;
}

// K_C: 32 rows x 1024 cols per block (256 threads, 4 cols/thread).
// W_out rows in registers (amortized over 32 rows); feats read per row-pair
// (wave-uniform addresses); float4 x loads, NT float4 stores.
__global__ __launch_bounds__(256) void kC_out(
    const float* __restrict__ x, const float* __restrict__ feats,
    const float* __restrict__ W_out, const float* __restrict__ b_out,
    const float* __restrict__ strength, float* __restrict__ out) {
    const int tid = threadIdx.x;
    const int row0 = blockIdx.x * 32;
    const int c0 = blockIdx.y * 1024 + tid * 4;

    float w[4][18];
#pragma unroll
    for (int cc = 0; cc < 4; ++cc) {
        const float2* wp2 = reinterpret_cast<const float2*>(W_out + (size_t)(c0 + cc) * 18);
#pragma unroll
        for (int k = 0; k < 9; ++k) { float2 t = wp2[k]; w[cc][2*k] = t.x; w[cc][2*k+1] = t.y; }
    }
    const floatx4 bo = *reinterpret_cast<const floatx4*>(b_out + c0);
    const float sabs = fabsf(strength[0]);

#pragma unroll 1
    for (int r = 0; r < 32; r += 2) {
        const int rowA = row0 + r, rowB = row0 + r + 1;
        const float* fA = feats + (size_t)rowA * 18;
        const float* fB = feats + (size_t)rowB * 18;
        const floatx4 xA = *reinterpret_cast<const floatx4*>(x + (size_t)rowA * DD + c0);
        const floatx4 xB = *reinterpret_cast<const floatx4*>(x + (size_t)rowB * DD + c0);
        floatx4 pA = bo, pB = bo;
#pragma unroll
        for (int k = 0; k < 18; ++k) {
            const float fa = fA[k], fb = fB[k];
            const floatx4 wk = { w[0][k], w[1][k], w[2][k], w[3][k] };
            pA += fa * wk;
            pB += fb * wk;
        }
        floatx4 oA, oB;
        oA.x = xA.x + fast_tanh(pA.x) * sabs;
        oA.y = xA.y + fast_tanh(pA.y) * sabs;
        oA.z = xA.z + fast_tanh(pA.z) * sabs;
        oA.w = xA.w + fast_tanh(pA.w) * sabs;
        oB.x = xB.x + fast_tanh(pB.x) * sabs;
        oB.y = xB.y + fast_tanh(pB.y) * sabs;
        oB.z = xB.z + fast_tanh(pB.z) * sabs;
        oB.w = xB.w + fast_tanh(pB.w) * sabs;
        __builtin_nontemporal_store(oA, reinterpret_cast<floatx4*>(out + (size_t)rowA * DD + c0));
        __builtin_nontemporal_store(oB, reinterpret_cast<floatx4*>(out + (size_t)rowB * DD + c0));
    }
}

extern "C" void kernel_launch(void* const* d_in, const int* in_sizes, int n_in,
                              void* d_out, int out_size, void* d_ws, size_t ws_size,
                              hipStream_t stream) {
    const float* x        = (const float*)d_in[0];
    const float* lorenz   = (const float*)d_in[1];
    const float* strength = (const float*)d_in[2];
    const float* W_in     = (const float*)d_in[3];
    const float* b_in     = (const float*)d_in[4];
    const float* W_out    = (const float*)d_in[5];
    const float* b_out    = (const float*)d_in[6];
    float* out = (float*)d_out;

    const int N = in_sizes[0] / DD;  // 16384
    float* state0 = (float*)d_ws;          // N*3 floats
    float* feats  = state0 + (size_t)N * 3; // N*18 floats

    kA_state0<<<N / 8, 256, 0, stream>>>(x, W_in, b_in, state0);
    kB_integrate<<<N / 256, 256, 0, stream>>>(state0, lorenz, feats);
    dim3 g3(N / 32, DD / 1024);
    kC_out<<<g3, 256, 0, stream>>>(x, feats, W_out, b_out, strength, out);
}

// Round 8
// 81.622 us; speedup vs baseline: 1.5622x; 1.5622x over previous
//
#include <hip/hip_runtime.h>
#include <math.h>

#define DD 2048
#define DTC 0.01f
#define NSTEPS 30

typedef float floatx4 __attribute__((ext_vector_type(4)));

__device__ __forceinline__ void lorenz_deriv(float x, float y, float z,
                                             float sigma, float rho, float beta,
                                             float& dx, float& dy, float& dz) {
    dx = sigma * (y - x);
    dy = x * (rho - z) - y;
    dz = x * y - beta * z;
}

__device__ __forceinline__ float fast_tanh(float p) {
    float e = __expf(2.0f * p);
    return 1.0f - __fdividef(2.0f, e + 1.0f);
}

// K_A: state0 = x @ W_in^T + b_in. 4 rows/block, 256 threads, thread owns
// 8 CONSECUTIVE cols (coalesced); all 8 x-loads hoisted for ILP.
__global__ __launch_bounds__(256) void kA_state0(
    const float* __restrict__ x, const float* __restrict__ W_in,
    const float* __restrict__ b_in, float* __restrict__ state0) {
    __shared__ float red[4][12];
    const int tid = threadIdx.x;
    const int lane = tid & 63;
    const int wv = tid >> 6;
    const int row0 = blockIdx.x * 4;
    const int c0 = tid * 8;

    // x tile: 4 rows x 8 cols -> 8 independent float4 loads, all in flight.
    floatx4 xr[4][2];
#pragma unroll
    for (int r = 0; r < 4; ++r) {
        const float* p = x + (size_t)(row0 + r) * DD + c0;
        xr[r][0] = *reinterpret_cast<const floatx4*>(p);
        xr[r][1] = *reinterpret_cast<const floatx4*>(p + 4);
    }
    // W_in slice: 3 x 8 cols (6 loads).
    floatx4 w[3][2];
#pragma unroll
    for (int k = 0; k < 3; ++k) {
        const float* p = W_in + (size_t)k * DD + c0;
        w[k][0] = *reinterpret_cast<const floatx4*>(p);
        w[k][1] = *reinterpret_cast<const floatx4*>(p + 4);
    }

    float s[4][3];
#pragma unroll
    for (int r = 0; r < 4; ++r) {
#pragma unroll
        for (int k = 0; k < 3; ++k) {
            floatx4 t = xr[r][0] * w[k][0] + xr[r][1] * w[k][1];
            s[r][k] = (t.x + t.y) + (t.z + t.w);
        }
    }

#pragma unroll
    for (int r = 0; r < 4; ++r) {
#pragma unroll
        for (int k = 0; k < 3; ++k) {
            float v = s[r][k];
#pragma unroll
            for (int off = 32; off > 0; off >>= 1) v += __shfl_xor(v, off, 64);
            if (lane == 0) red[wv][r * 3 + k] = v;
        }
    }
    __syncthreads();
    if (tid < 12) {
        float v = red[0][tid] + red[1][tid] + red[2][tid] + red[3][tid] + b_in[tid % 3];
        state0[(size_t)(row0 + tid / 3) * 3 + (tid % 3)] = v;
    }
}

// K_B: one thread per row, all 64 lanes integrate concurrently (packed waves).
__global__ __launch_bounds__(256) void kB_integrate(
    const float* __restrict__ state0, const float* __restrict__ lorenz,
    float* __restrict__ feats) {
    const int row = blockIdx.x * 256 + threadIdx.x;
    const float sigma = fmaxf(fabsf(lorenz[0]), 0.1f);
    const float rho   = fmaxf(fabsf(lorenz[1]), 0.1f);
    const float beta  = fmaxf(fabsf(lorenz[2]), 0.1f);

    float sx = state0[(size_t)row * 3 + 0];
    float sy = state0[(size_t)row * 3 + 1];
    float sz = state0[(size_t)row * 3 + 2];
    const float ix = sx, iy = sy, iz = sz;
    float sux = sx, suy = sy, suz = sz;
    float sqx = sx * sx, sqy = sy * sy, sqz = sz * sz;
    float mnx = sx, mny = sy, mnz = sz;
    float mxx = sx, mxy = sy, mxz = sz;
#pragma unroll 1
    for (int t = 0; t < NSTEPS; ++t) {
        float k1x, k1y, k1z, k2x, k2y, k2z, k3x, k3y, k3z, k4x, k4y, k4z;
        float ax, ay, az;
        lorenz_deriv(sx, sy, sz, sigma, rho, beta, k1x, k1y, k1z);
        ax = sx + 0.5f * DTC * k1x; ay = sy + 0.5f * DTC * k1y; az = sz + 0.5f * DTC * k1z;
        lorenz_deriv(ax, ay, az, sigma, rho, beta, k2x, k2y, k2z);
        ax = sx + 0.5f * DTC * k2x; ay = sy + 0.5f * DTC * k2y; az = sz + 0.5f * DTC * k2z;
        lorenz_deriv(ax, ay, az, sigma, rho, beta, k3x, k3y, k3z);
        ax = sx + DTC * k3x; ay = sy + DTC * k3y; az = sz + DTC * k3z;
        lorenz_deriv(ax, ay, az, sigma, rho, beta, k4x, k4y, k4z);
        sx += (DTC / 6.0f) * (k1x + 2.0f * k2x + 2.0f * k3x + k4x);
        sy += (DTC / 6.0f) * (k1y + 2.0f * k2y + 2.0f * k3y + k4y);
        sz += (DTC / 6.0f) * (k1z + 2.0f * k2z + 2.0f * k3z + k4z);
        sux += sx; suy += sy; suz += sz;
        sqx += sx * sx; sqy += sy * sy; sqz += sz * sz;
        mnx = fminf(mnx, sx); mny = fminf(mny, sy); mnz = fminf(mnz, sz);
        mxx = fmaxf(mxx, sx); mxy = fmaxf(mxy, sy); mxz = fmaxf(mxz, sz);
    }
    const float inv31 = 1.0f / 31.0f;
    const float inv30 = 1.0f / 30.0f;
    const float mex = sux * inv31, mey = suy * inv31, mez = suz * inv31;
    const float vax = fmaxf((sqx - sux * mex) * inv30, 0.0f);
    const float vay = fmaxf((sqy - suy * mey) * inv30, 0.0f);
    const float vaz = fmaxf((sqz - suz * mez) * inv30, 0.0f);
    float* f = feats + (size_t)row * 18;
    f[0]  = ix;  f[1]  = iy;  f[2]  = iz;
    f[3]  = sx;  f[4]  = sy;  f[5]  = sz;
    f[6]  = mex; f[7]  = mey; f[8]  = mez;
    f[9]  = sqrtf(vax); f[10] = sqrtf(vay); f[11] = sqrtf(vaz);
    f[12] = mnx; f[13] = mny; f[14] = mnz;
    f[15] = mxx; f[16] = mxy; f[17] = mxz;
}

// K_C: 32 rows x 1024 cols per block (256 threads, 4 cols/thread).
// W_out rows in registers (amortized over 32 rows); feats read per row-pair
// (wave-uniform addresses); float4 x loads, NT float4 stores.
__global__ __launch_bounds__(256) void kC_out(
    const float* __restrict__ x, const float* __restrict__ feats,
    const float* __restrict__ W_out, const float* __restrict__ b_out,
    const float* __restrict__ strength, float* __restrict__ out) {
    const int tid = threadIdx.x;
    const int row0 = blockIdx.x * 32;
    const int c0 = blockIdx.y * 1024 + tid * 4;

    float w[4][18];
#pragma unroll
    for (int cc = 0; cc < 4; ++cc) {
        const float2* wp2 = reinterpret_cast<const float2*>(W_out + (size_t)(c0 + cc) * 18);
#pragma unroll
        for (int k = 0; k < 9; ++k) { float2 t = wp2[k]; w[cc][2*k] = t.x; w[cc][2*k+1] = t.y; }
    }
    const floatx4 bo = *reinterpret_cast<const floatx4*>(b_out + c0);
    const float sabs = fabsf(strength[0]);

#pragma unroll 1
    for (int r = 0; r < 32; r += 2) {
        const int rowA = row0 + r, rowB = row0 + r + 1;
        const float* fA = feats + (size_t)rowA * 18;
        const float* fB = feats + (size_t)rowB * 18;
        const floatx4 xA = *reinterpret_cast<const floatx4*>(x + (size_t)rowA * DD + c0);
        const floatx4 xB = *reinterpret_cast<const floatx4*>(x + (size_t)rowB * DD + c0);
        floatx4 pA = bo, pB = bo;
#pragma unroll
        for (int k = 0; k < 18; ++k) {
            const float fa = fA[k], fb = fB[k];
            const floatx4 wk = { w[0][k], w[1][k], w[2][k], w[3][k] };
            pA += fa * wk;
            pB += fb * wk;
        }
        floatx4 oA, oB;
        oA.x = xA.x + fast_tanh(pA.x) * sabs;
        oA.y = xA.y + fast_tanh(pA.y) * sabs;
        oA.z = xA.z + fast_tanh(pA.z) * sabs;
        oA.w = xA.w + fast_tanh(pA.w) * sabs;
        oB.x = xB.x + fast_tanh(pB.x) * sabs;
        oB.y = xB.y + fast_tanh(pB.y) * sabs;
        oB.z = xB.z + fast_tanh(pB.z) * sabs;
        oB.w = xB.w + fast_tanh(pB.w) * sabs;
        __builtin_nontemporal_store(oA, reinterpret_cast<floatx4*>(out + (size_t)rowA * DD + c0));
        __builtin_nontemporal_store(oB, reinterpret_cast<floatx4*>(out + (size_t)rowB * DD + c0));
    }
}

extern "C" void kernel_launch(void* const* d_in, const int* in_sizes, int n_in,
                              void* d_out, int out_size, void* d_ws, size_t ws_size,
                              hipStream_t stream) {
    const float* x        = (const float*)d_in[0];
    const float* lorenz   = (const float*)d_in[1];
    const float* strength = (const float*)d_in[2];
    const float* W_in     = (const float*)d_in[3];
    const float* b_in     = (const float*)d_in[4];
    const float* W_out    = (const float*)d_in[5];
    const float* b_out    = (const float*)d_in[6];
    float* out = (float*)d_out;

    const int N = in_sizes[0] / DD;  // 16384
    float* state0 = (float*)d_ws;          // N*3 floats
    float* feats  = state0 + (size_t)N * 3; // N*18 floats

    kA_state0<<<N / 4, 256, 0, stream>>>(x, W_in, b_in, state0);
    kB_integrate<<<N / 256, 256, 0, stream>>>(state0, lorenz, feats);
    dim3 g3(N / 32, DD / 1024);
    kC_out<<<g3, 256, 0, stream>>>(x, feats, W_out, b_out, strength, out);
}

// Round 9
// 79.666 us; speedup vs baseline: 1.6006x; 1.0246x over previous
//
#include <hip/hip_runtime.h>
#include <math.h>

#define DD 2048
#define DTC 0.01f
#define NSTEPS 30

typedef float floatx4 __attribute__((ext_vector_type(4)));

__device__ __forceinline__ void lorenz_deriv(float x, float y, float z,
                                             float sigma, float rho, float beta,
                                             float& dx, float& dy, float& dz) {
    dx = sigma * (y - x);
    dy = x * (rho - z) - y;
    dz = x * y - beta * z;
}

__device__ __forceinline__ float fast_tanh(float p) {
    float e = __expf(2.0f * p);
    return 1.0f - __fdividef(2.0f, e + 1.0f);
}

// K_A: state0 = x @ W_in^T + b_in. 4 rows/block, 256 threads, thread owns
// 8 consecutive cols (coalesced). Reduction: 2-step butterfly + LDS combine
// (DS ops/thread ~35 vs 72 for the full 6-step butterfly).
__global__ __launch_bounds__(256) void kA_state0(
    const float* __restrict__ x, const float* __restrict__ W_in,
    const float* __restrict__ b_in, float* __restrict__ state0) {
    __shared__ float g_lds[4][16][13];   // [wave][group][12 partials + pad]
    const int tid = threadIdx.x;
    const int lane = tid & 63;
    const int wv = tid >> 6;
    const int row0 = blockIdx.x * 4;
    const int c0 = tid * 8;

    // x tile: 4 rows x 8 cols -> 8 independent float4 loads in flight.
    floatx4 xr[4][2];
#pragma unroll
    for (int r = 0; r < 4; ++r) {
        const float* p = x + (size_t)(row0 + r) * DD + c0;
        xr[r][0] = *reinterpret_cast<const floatx4*>(p);
        xr[r][1] = *reinterpret_cast<const floatx4*>(p + 4);
    }
    floatx4 w[3][2];
#pragma unroll
    for (int k = 0; k < 3; ++k) {
        const float* p = W_in + (size_t)k * DD + c0;
        w[k][0] = *reinterpret_cast<const floatx4*>(p);
        w[k][1] = *reinterpret_cast<const floatx4*>(p + 4);
    }

    float s[12];
#pragma unroll
    for (int r = 0; r < 4; ++r) {
#pragma unroll
        for (int k = 0; k < 3; ++k) {
            floatx4 t = xr[r][0] * w[k][0] + xr[r][1] * w[k][1];
            s[r * 3 + k] = (t.x + t.y) + (t.z + t.w);
        }
    }

    // Stage 1: 2-step butterfly; lanes 0..15 then hold the sum of
    // {l, l+16, l+32, l+48}.
#pragma unroll
    for (int o = 0; o < 12; ++o) {
        s[o] += __shfl_xor(s[o], 32, 64);
        s[o] += __shfl_xor(s[o], 16, 64);
    }
    if (lane < 16) {
#pragma unroll
        for (int o = 0; o < 12; ++o) g_lds[wv][lane][o] = s[o];
    }
    __syncthreads();

    // Stage 2: 192 threads; output o = tid>>4, slot j = tid&15.
    // Each sums the 4 wave-partials of group j, then a 4-step 16-lane
    // butterfly combines the 16 groups.
    if (tid < 192) {
        const int o = tid >> 4;
        const int j = tid & 15;
        float v = g_lds[0][j][o] + g_lds[1][j][o] + g_lds[2][j][o] + g_lds[3][j][o];
#pragma unroll
        for (int off = 1; off < 16; off <<= 1) v += __shfl_xor(v, off, 64);
        if (j == 0) {
            state0[(size_t)(row0 + o / 3) * 3 + (o % 3)] = v + b_in[o % 3];
        }
    }
}

// K_B: one thread per row, all 64 lanes integrate concurrently.
__global__ __launch_bounds__(256) void kB_integrate(
    const float* __restrict__ state0, const float* __restrict__ lorenz,
    float* __restrict__ feats) {
    const int row = blockIdx.x * 256 + threadIdx.x;
    const float sigma = fmaxf(fabsf(lorenz[0]), 0.1f);
    const float rho   = fmaxf(fabsf(lorenz[1]), 0.1f);
    const float beta  = fmaxf(fabsf(lorenz[2]), 0.1f);

    float sx = state0[(size_t)row * 3 + 0];
    float sy = state0[(size_t)row * 3 + 1];
    float sz = state0[(size_t)row * 3 + 2];
    const float ix = sx, iy = sy, iz = sz;
    float sux = sx, suy = sy, suz = sz;
    float sqx = sx * sx, sqy = sy * sy, sqz = sz * sz;
    float mnx = sx, mny = sy, mnz = sz;
    float mxx = sx, mxy = sy, mxz = sz;
#pragma unroll 1
    for (int t = 0; t < NSTEPS; ++t) {
        float k1x, k1y, k1z, k2x, k2y, k2z, k3x, k3y, k3z, k4x, k4y, k4z;
        float ax, ay, az;
        lorenz_deriv(sx, sy, sz, sigma, rho, beta, k1x, k1y, k1z);
        ax = sx + 0.5f * DTC * k1x; ay = sy + 0.5f * DTC * k1y; az = sz + 0.5f * DTC * k1z;
        lorenz_deriv(ax, ay, az, sigma, rho, beta, k2x, k2y, k2z);
        ax = sx + 0.5f * DTC * k2x; ay = sy + 0.5f * DTC * k2y; az = sz + 0.5f * DTC * k2z;
        lorenz_deriv(ax, ay, az, sigma, rho, beta, k3x, k3y, k3z);
        ax = sx + DTC * k3x; ay = sy + DTC * k3y; az = sz + DTC * k3z;
        lorenz_deriv(ax, ay, az, sigma, rho, beta, k4x, k4y, k4z);
        sx += (DTC / 6.0f) * (k1x + 2.0f * k2x + 2.0f * k3x + k4x);
        sy += (DTC / 6.0f) * (k1y + 2.0f * k2y + 2.0f * k3y + k4y);
        sz += (DTC / 6.0f) * (k1z + 2.0f * k2z + 2.0f * k3z + k4z);
        sux += sx; suy += sy; suz += sz;
        sqx += sx * sx; sqy += sy * sy; sqz += sz * sz;
        mnx = fminf(mnx, sx); mny = fminf(mny, sy); mnz = fminf(mnz, sz);
        mxx = fmaxf(mxx, sx); mxy = fmaxf(mxy, sy); mxz = fmaxf(mxz, sz);
    }
    const float inv31 = 1.0f / 31.0f;
    const float inv30 = 1.0f / 30.0f;
    const float mex = sux * inv31, mey = suy * inv31, mez = suz * inv31;
    const float vax = fmaxf((sqx - sux * mex) * inv30, 0.0f);
    const float vay = fmaxf((sqy - suy * mey) * inv30, 0.0f);
    const float vaz = fmaxf((sqz - suz * mez) * inv30, 0.0f);
    float* f = feats + (size_t)row * 18;
    f[0]  = ix;  f[1]  = iy;  f[2]  = iz;
    f[3]  = sx;  f[4]  = sy;  f[5]  = sz;
    f[6]  = mex; f[7]  = mey; f[8]  = mez;
    f[9]  = sqrtf(vax); f[10] = sqrtf(vay); f[11] = sqrtf(vaz);
    f[12] = mnx; f[13] = mny; f[14] = mnz;
    f[15] = mxx; f[16] = mxy; f[17] = mxz;
}

// K_C: 32 rows x 1024 cols per block (256 threads, 4 cols/thread).
// feats tile staged to LDS (broadcast ds_reads); W_out rows in registers;
// float4 x loads; NT float4 stores.
__global__ __launch_bounds__(256) void kC_out(
    const float* __restrict__ x, const float* __restrict__ feats,
    const float* __restrict__ W_out, const float* __restrict__ b_out,
    const float* __restrict__ strength, float* __restrict__ out) {
    __shared__ float f_lds[32 * 18];   // 576 floats, contiguous in feats
    const int tid = threadIdx.x;
    const int row0 = blockIdx.x * 32;
    const int c0 = blockIdx.y * 1024 + tid * 4;

    {
        const float* src = feats + (size_t)row0 * 18;
        f_lds[tid] = src[tid];
        f_lds[tid + 256] = src[tid + 256];
        if (tid < 64) f_lds[tid + 512] = src[tid + 512];
    }

    float w[4][18];
#pragma unroll
    for (int cc = 0; cc < 4; ++cc) {
        const float2* wp2 = reinterpret_cast<const float2*>(W_out + (size_t)(c0 + cc) * 18);
#pragma unroll
        for (int k = 0; k < 9; ++k) { float2 t = wp2[k]; w[cc][2*k] = t.x; w[cc][2*k+1] = t.y; }
    }
    const floatx4 bo = *reinterpret_cast<const floatx4*>(b_out + c0);
    const float sabs = fabsf(strength[0]);
    __syncthreads();

#pragma unroll 1
    for (int r = 0; r < 32; r += 2) {
        const int rowA = row0 + r, rowB = row0 + r + 1;
        const float* fA = f_lds + r * 18;
        const float* fB = f_lds + (r + 1) * 18;
        const floatx4 xA = *reinterpret_cast<const floatx4*>(x + (size_t)rowA * DD + c0);
        const floatx4 xB = *reinterpret_cast<const floatx4*>(x + (size_t)rowB * DD + c0);
        floatx4 pA = bo, pB = bo;
#pragma unroll
        for (int k = 0; k < 18; ++k) {
            const float fa = fA[k], fb = fB[k];
            const floatx4 wk = { w[0][k], w[1][k], w[2][k], w[3][k] };
            pA += fa * wk;
            pB += fb * wk;
        }
        floatx4 oA, oB;
        oA.x = xA.x + fast_tanh(pA.x) * sabs;
        oA.y = xA.y + fast_tanh(pA.y) * sabs;
        oA.z = xA.z + fast_tanh(pA.z) * sabs;
        oA.w = xA.w + fast_tanh(pA.w) * sabs;
        oB.x = xB.x + fast_tanh(pB.x) * sabs;
        oB.y = xB.y + fast_tanh(pB.y) * sabs;
        oB.z = xB.z + fast_tanh(pB.z) * sabs;
        oB.w = xB.w + fast_tanh(pB.w) * sabs;
        __builtin_nontemporal_store(oA, reinterpret_cast<floatx4*>(out + (size_t)rowA * DD + c0));
        __builtin_nontemporal_store(oB, reinterpret_cast<floatx4*>(out + (size_t)rowB * DD + c0));
    }
}

extern "C" void kernel_launch(void* const* d_in, const int* in_sizes, int n_in,
                              void* d_out, int out_size, void* d_ws, size_t ws_size,
                              hipStream_t stream) {
    const float* x        = (const float*)d_in[0];
    const float* lorenz   = (const float*)d_in[1];
    const float* strength = (const float*)d_in[2];
    const float* W_in     = (const float*)d_in[3];
    const float* b_in     = (const float*)d_in[4];
    const float* W_out    = (const float*)d_in[5];
    const float* b_out    = (const float*)d_in[6];
    float* out = (float*)d_out;

    const int N = in_sizes[0] / DD;  // 16384
    float* state0 = (float*)d_ws;           // N*3 floats
    float* feats  = state0 + (size_t)N * 3; // N*18 floats

    kA_state0<<<N / 4, 256, 0, stream>>>(x, W_in, b_in, state0);
    kB_integrate<<<N / 256, 256, 0, stream>>>(state0, lorenz, feats);
    dim3 g3(N / 32, DD / 1024);
    kC_out<<<g3, 256, 0, stream>>>(x, feats, W_out, b_out, strength, out);
}

// Round 10
// 77.914 us; speedup vs baseline: 1.6366x; 1.0225x over previous
//
#include <hip/hip_runtime.h>
#include <math.h>

#define DD 2048
#define DTC 0.01f
#define NSTEPS 30

typedef float floatx4 __attribute__((ext_vector_type(4)));

__device__ __forceinline__ void lorenz_deriv(float x, float y, float z,
                                             float sigma, float rho, float beta,
                                             float& dx, float& dy, float& dz) {
    dx = sigma * (y - x);
    dy = x * (rho - z) - y;
    dz = x * y - beta * z;
}

__device__ __forceinline__ float fast_tanh(float p) {
    float e = __expf(2.0f * p);
    return 1.0f - __fdividef(2.0f, e + 1.0f);
}

// K_A: state0 = x @ W_in^T + b_in (4 rows/block, coalesced, butterfly+LDS
// reduce). Side job: blocks 0..143 transpose W_out[2048][18] -> wsT[18][2048]
// (after the state0 path so it overlaps other blocks' streaming).
__global__ __launch_bounds__(256) void kA_state0(
    const float* __restrict__ x, const float* __restrict__ W_in,
    const float* __restrict__ b_in, float* __restrict__ state0,
    const float* __restrict__ W_out, float* __restrict__ wsT) {
    __shared__ float g_lds[4][16][13];
    const int tid = threadIdx.x;
    const int lane = tid & 63;
    const int wv = tid >> 6;
    const int row0 = blockIdx.x * 4;
    const int c0 = tid * 8;

    floatx4 xr[4][2];
#pragma unroll
    for (int r = 0; r < 4; ++r) {
        const float* p = x + (size_t)(row0 + r) * DD + c0;
        xr[r][0] = *reinterpret_cast<const floatx4*>(p);
        xr[r][1] = *reinterpret_cast<const floatx4*>(p + 4);
    }
    floatx4 w[3][2];
#pragma unroll
    for (int k = 0; k < 3; ++k) {
        const float* p = W_in + (size_t)k * DD + c0;
        w[k][0] = *reinterpret_cast<const floatx4*>(p);
        w[k][1] = *reinterpret_cast<const floatx4*>(p + 4);
    }

    float s[12];
#pragma unroll
    for (int r = 0; r < 4; ++r) {
#pragma unroll
        for (int k = 0; k < 3; ++k) {
            floatx4 t = xr[r][0] * w[k][0] + xr[r][1] * w[k][1];
            s[r * 3 + k] = (t.x + t.y) + (t.z + t.w);
        }
    }

#pragma unroll
    for (int o = 0; o < 12; ++o) {
        s[o] += __shfl_xor(s[o], 32, 64);
        s[o] += __shfl_xor(s[o], 16, 64);
    }
    if (lane < 16) {
#pragma unroll
        for (int o = 0; o < 12; ++o) g_lds[wv][lane][o] = s[o];
    }
    __syncthreads();

    if (tid < 192) {
        const int o = tid >> 4;
        const int j = tid & 15;
        float v = g_lds[0][j][o] + g_lds[1][j][o] + g_lds[2][j][o] + g_lds[3][j][o];
#pragma unroll
        for (int off = 1; off < 16; off <<= 1) v += __shfl_xor(v, off, 64);
        if (j == 0) {
            state0[(size_t)(row0 + o / 3) * 3 + (o % 3)] = v + b_in[o % 3];
        }
    }

    // W_out transpose side job (36864 elements over 144 blocks).
    if (blockIdx.x < 144) {
        const int oidx = blockIdx.x * 256 + tid;
        const int k = oidx >> 11;
        const int c = oidx & 2047;
        wsT[oidx] = W_out[c * 18 + k];
    }
}

// K_B: one thread per row, all 64 lanes integrate concurrently.
__global__ __launch_bounds__(256) void kB_integrate(
    const float* __restrict__ state0, const float* __restrict__ lorenz,
    float* __restrict__ feats) {
    const int row = blockIdx.x * 256 + threadIdx.x;
    const float sigma = fmaxf(fabsf(lorenz[0]), 0.1f);
    const float rho   = fmaxf(fabsf(lorenz[1]), 0.1f);
    const float beta  = fmaxf(fabsf(lorenz[2]), 0.1f);

    float sx = state0[(size_t)row * 3 + 0];
    float sy = state0[(size_t)row * 3 + 1];
    float sz = state0[(size_t)row * 3 + 2];
    const float ix = sx, iy = sy, iz = sz;
    float sux = sx, suy = sy, suz = sz;
    float sqx = sx * sx, sqy = sy * sy, sqz = sz * sz;
    float mnx = sx, mny = sy, mnz = sz;
    float mxx = sx, mxy = sy, mxz = sz;
#pragma unroll 1
    for (int t = 0; t < NSTEPS; ++t) {
        float k1x, k1y, k1z, k2x, k2y, k2z, k3x, k3y, k3z, k4x, k4y, k4z;
        float ax, ay, az;
        lorenz_deriv(sx, sy, sz, sigma, rho, beta, k1x, k1y, k1z);
        ax = sx + 0.5f * DTC * k1x; ay = sy + 0.5f * DTC * k1y; az = sz + 0.5f * DTC * k1z;
        lorenz_deriv(ax, ay, az, sigma, rho, beta, k2x, k2y, k2z);
        ax = sx + 0.5f * DTC * k2x; ay = sy + 0.5f * DTC * k2y; az = sz + 0.5f * DTC * k2z;
        lorenz_deriv(ax, ay, az, sigma, rho, beta, k3x, k3y, k3z);
        ax = sx + DTC * k3x; ay = sy + DTC * k3y; az = sz + DTC * k3z;
        lorenz_deriv(ax, ay, az, sigma, rho, beta, k4x, k4y, k4z);
        sx += (DTC / 6.0f) * (k1x + 2.0f * k2x + 2.0f * k3x + k4x);
        sy += (DTC / 6.0f) * (k1y + 2.0f * k2y + 2.0f * k3y + k4y);
        sz += (DTC / 6.0f) * (k1z + 2.0f * k2z + 2.0f * k3z + k4z);
        sux += sx; suy += sy; suz += sz;
        sqx += sx * sx; sqy += sy * sy; sqz += sz * sz;
        mnx = fminf(mnx, sx); mny = fminf(mny, sy); mnz = fminf(mnz, sz);
        mxx = fmaxf(mxx, sx); mxy = fmaxf(mxy, sy); mxz = fmaxf(mxz, sz);
    }
    const float inv31 = 1.0f / 31.0f;
    const float inv30 = 1.0f / 30.0f;
    const float mex = sux * inv31, mey = suy * inv31, mez = suz * inv31;
    const float vax = fmaxf((sqx - sux * mex) * inv30, 0.0f);
    const float vay = fmaxf((sqy - suy * mey) * inv30, 0.0f);
    const float vaz = fmaxf((sqz - suz * mez) * inv30, 0.0f);
    float* f = feats + (size_t)row * 18;
    f[0]  = ix;  f[1]  = iy;  f[2]  = iz;
    f[3]  = sx;  f[4]  = sy;  f[5]  = sz;
    f[6]  = mex; f[7]  = mey; f[8]  = mez;
    f[9]  = sqrtf(vax); f[10] = sqrtf(vay); f[11] = sqrtf(vaz);
    f[12] = mnx; f[13] = mny; f[14] = mnz;
    f[15] = mxx; f[16] = mxy; f[17] = mxz;
}

// K_C: 32 rows x 1024 cols per block (256 threads, 4 cols/thread).
// Weights from transposed wsT: 18 coalesced float4 loads (vs 36 strided
// float2). feats tile in LDS (broadcast reads); float4 x; NT stores.
__global__ __launch_bounds__(256) void kC_out(
    const float* __restrict__ x, const float* __restrict__ feats,
    const float* __restrict__ wsT, const float* __restrict__ b_out,
    const float* __restrict__ strength, float* __restrict__ out) {
    __shared__ float f_lds[32 * 18];
    const int tid = threadIdx.x;
    const int row0 = blockIdx.x * 32;
    const int c0 = blockIdx.y * 1024 + tid * 4;

    {
        const float* src = feats + (size_t)row0 * 18;
        f_lds[tid] = src[tid];
        f_lds[tid + 256] = src[tid + 256];
        if (tid < 64) f_lds[tid + 512] = src[tid + 512];
    }

    floatx4 wk[18];
#pragma unroll
    for (int k = 0; k < 18; ++k) {
        wk[k] = *reinterpret_cast<const floatx4*>(wsT + (size_t)k * DD + c0);
    }
    const floatx4 bo = *reinterpret_cast<const floatx4*>(b_out + c0);
    const float sabs = fabsf(strength[0]);
    __syncthreads();

#pragma unroll 1
    for (int r = 0; r < 32; r += 2) {
        const int rowA = row0 + r, rowB = row0 + r + 1;
        const float* fA = f_lds + r * 18;
        const float* fB = f_lds + (r + 1) * 18;
        const floatx4 xA = *reinterpret_cast<const floatx4*>(x + (size_t)rowA * DD + c0);
        const floatx4 xB = *reinterpret_cast<const floatx4*>(x + (size_t)rowB * DD + c0);
        floatx4 pA = bo, pB = bo;
#pragma unroll
        for (int k = 0; k < 18; ++k) {
            pA += fA[k] * wk[k];
            pB += fB[k] * wk[k];
        }
        floatx4 oA, oB;
        oA.x = xA.x + fast_tanh(pA.x) * sabs;
        oA.y = xA.y + fast_tanh(pA.y) * sabs;
        oA.z = xA.z + fast_tanh(pA.z) * sabs;
        oA.w = xA.w + fast_tanh(pA.w) * sabs;
        oB.x = xB.x + fast_tanh(pB.x) * sabs;
        oB.y = xB.y + fast_tanh(pB.y) * sabs;
        oB.z = xB.z + fast_tanh(pB.z) * sabs;
        oB.w = xB.w + fast_tanh(pB.w) * sabs;
        __builtin_nontemporal_store(oA, reinterpret_cast<floatx4*>(out + (size_t)rowA * DD + c0));
        __builtin_nontemporal_store(oB, reinterpret_cast<floatx4*>(out + (size_t)rowB * DD + c0));
    }
}

extern "C" void kernel_launch(void* const* d_in, const int* in_sizes, int n_in,
                              void* d_out, int out_size, void* d_ws, size_t ws_size,
                              hipStream_t stream) {
    const float* x        = (const float*)d_in[0];
    const float* lorenz   = (const float*)d_in[1];
    const float* strength = (const float*)d_in[2];
    const float* W_in     = (const float*)d_in[3];
    const float* b_in     = (const float*)d_in[4];
    const float* W_out    = (const float*)d_in[5];
    const float* b_out    = (const float*)d_in[6];
    float* out = (float*)d_out;

    const int N = in_sizes[0] / DD;  // 16384
    float* state0 = (float*)d_ws;            // N*3 floats
    float* feats  = state0 + (size_t)N * 3;  // N*18 floats
    float* wsT    = feats + (size_t)N * 18;  // 18*2048 floats = 147 KB

    kA_state0<<<N / 4, 256, 0, stream>>>(x, W_in, b_in, state0, W_out, wsT);
    kB_integrate<<<N / 256, 256, 0, stream>>>(state0, lorenz, feats);
    dim3 g3(N / 32, DD / 1024);
    kC_out<<<g3, 256, 0, stream>>>(x, feats, wsT, b_out, strength, out);
}

// Round 11
// 77.375 us; speedup vs baseline: 1.6480x; 1.0070x over previous
//
#include <hip/hip_runtime.h>
#include <math.h>

#define DD 2048
#define DTC 0.01f
#define NSTEPS 30

typedef float floatx4 __attribute__((ext_vector_type(4)));

__device__ __forceinline__ void lorenz_deriv(float x, float y, float z,
                                             float sigma, float rho, float beta,
                                             float& dx, float& dy, float& dz) {
    dx = sigma * (y - x);
    dy = x * (rho - z) - y;
    dz = x * y - beta * z;
}

__device__ __forceinline__ float fast_tanh(float p) {
    float e = __expf(2.0f * p);
    return 1.0f - __fdividef(2.0f, e + 1.0f);
}

// K_A: state0 = x @ W_in^T + b_in. 4 rows/block, 256 threads. Thread owns
// cols {4t..4t+3} and {1024+4t..1024+4t+3}: every wave-load instruction is a
// packed 1KB segment (lane stride == access width). Butterfly+LDS reduce.
// Side job: blocks 0..143 transpose W_out -> wsT.
__global__ __launch_bounds__(256) void kA_state0(
    const float* __restrict__ x, const float* __restrict__ W_in,
    const float* __restrict__ b_in, float* __restrict__ state0,
    const float* __restrict__ W_out, float* __restrict__ wsT) {
    __shared__ float g_lds[4][16][13];
    const int tid = threadIdx.x;
    const int lane = tid & 63;
    const int wv = tid >> 6;
    const int row0 = blockIdx.x * 4;
    const int c0 = tid * 4;          // first-half columns (packed)
    const int c1 = 1024 + tid * 4;   // second-half columns (packed)

    // x tile: 4 rows x (2 packed float4) -> 8 fully-coalesced loads in flight.
    floatx4 xr0[4], xr1[4];
#pragma unroll
    for (int r = 0; r < 4; ++r) {
        const float* p = x + (size_t)(row0 + r) * DD;
        xr0[r] = *reinterpret_cast<const floatx4*>(p + c0);
        xr1[r] = *reinterpret_cast<const floatx4*>(p + c1);
    }
    floatx4 w0[3], w1[3];
#pragma unroll
    for (int k = 0; k < 3; ++k) {
        const float* p = W_in + (size_t)k * DD;
        w0[k] = *reinterpret_cast<const floatx4*>(p + c0);
        w1[k] = *reinterpret_cast<const floatx4*>(p + c1);
    }

    float s[12];
#pragma unroll
    for (int r = 0; r < 4; ++r) {
#pragma unroll
        for (int k = 0; k < 3; ++k) {
            floatx4 t = xr0[r] * w0[k] + xr1[r] * w1[k];
            s[r * 3 + k] = (t.x + t.y) + (t.z + t.w);
        }
    }

    // Stage 1: 2-step butterfly; lanes 0..15 hold sum of {l,l+16,l+32,l+48}.
#pragma unroll
    for (int o = 0; o < 12; ++o) {
        s[o] += __shfl_xor(s[o], 32, 64);
        s[o] += __shfl_xor(s[o], 16, 64);
    }
    if (lane < 16) {
#pragma unroll
        for (int o = 0; o < 12; ++o) g_lds[wv][lane][o] = s[o];
    }
    __syncthreads();

    // Stage 2: 192 threads; output o = tid>>4, slot j = tid&15.
    if (tid < 192) {
        const int o = tid >> 4;
        const int j = tid & 15;
        float v = g_lds[0][j][o] + g_lds[1][j][o] + g_lds[2][j][o] + g_lds[3][j][o];
#pragma unroll
        for (int off = 1; off < 16; off <<= 1) v += __shfl_xor(v, off, 64);
        if (j == 0) {
            state0[(size_t)(row0 + o / 3) * 3 + (o % 3)] = v + b_in[o % 3];
        }
    }

    // W_out transpose side job (36864 elements over 144 blocks).
    if (blockIdx.x < 144) {
        const int oidx = blockIdx.x * 256 + tid;
        const int k = oidx >> 11;
        const int c = oidx & 2047;
        wsT[oidx] = W_out[c * 18 + k];
    }
}

// K_B: one thread per row, all 64 lanes integrate concurrently.
__global__ __launch_bounds__(256) void kB_integrate(
    const float* __restrict__ state0, const float* __restrict__ lorenz,
    float* __restrict__ feats) {
    const int row = blockIdx.x * 256 + threadIdx.x;
    const float sigma = fmaxf(fabsf(lorenz[0]), 0.1f);
    const float rho   = fmaxf(fabsf(lorenz[1]), 0.1f);
    const float beta  = fmaxf(fabsf(lorenz[2]), 0.1f);

    float sx = state0[(size_t)row * 3 + 0];
    float sy = state0[(size_t)row * 3 + 1];
    float sz = state0[(size_t)row * 3 + 2];
    const float ix = sx, iy = sy, iz = sz;
    float sux = sx, suy = sy, suz = sz;
    float sqx = sx * sx, sqy = sy * sy, sqz = sz * sz;
    float mnx = sx, mny = sy, mnz = sz;
    float mxx = sx, mxy = sy, mxz = sz;
#pragma unroll 1
    for (int t = 0; t < NSTEPS; ++t) {
        float k1x, k1y, k1z, k2x, k2y, k2z, k3x, k3y, k3z, k4x, k4y, k4z;
        float ax, ay, az;
        lorenz_deriv(sx, sy, sz, sigma, rho, beta, k1x, k1y, k1z);
        ax = sx + 0.5f * DTC * k1x; ay = sy + 0.5f * DTC * k1y; az = sz + 0.5f * DTC * k1z;
        lorenz_deriv(ax, ay, az, sigma, rho, beta, k2x, k2y, k2z);
        ax = sx + 0.5f * DTC * k2x; ay = sy + 0.5f * DTC * k2y; az = sz + 0.5f * DTC * k2z;
        lorenz_deriv(ax, ay, az, sigma, rho, beta, k3x, k3y, k3z);
        ax = sx + DTC * k3x; ay = sy + DTC * k3y; az = sz + DTC * k3z;
        lorenz_deriv(ax, ay, az, sigma, rho, beta, k4x, k4y, k4z);
        sx += (DTC / 6.0f) * (k1x + 2.0f * k2x + 2.0f * k3x + k4x);
        sy += (DTC / 6.0f) * (k1y + 2.0f * k2y + 2.0f * k3y + k4y);
        sz += (DTC / 6.0f) * (k1z + 2.0f * k2z + 2.0f * k3z + k4z);
        sux += sx; suy += sy; suz += sz;
        sqx += sx * sx; sqy += sy * sy; sqz += sz * sz;
        mnx = fminf(mnx, sx); mny = fminf(mny, sy); mnz = fminf(mnz, sz);
        mxx = fmaxf(mxx, sx); mxy = fmaxf(mxy, sy); mxz = fmaxf(mxz, sz);
    }
    const float inv31 = 1.0f / 31.0f;
    const float inv30 = 1.0f / 30.0f;
    const float mex = sux * inv31, mey = suy * inv31, mez = suz * inv31;
    const float vax = fmaxf((sqx - sux * mex) * inv30, 0.0f);
    const float vay = fmaxf((sqy - suy * mey) * inv30, 0.0f);
    const float vaz = fmaxf((sqz - suz * mez) * inv30, 0.0f);
    float* f = feats + (size_t)row * 18;
    f[0]  = ix;  f[1]  = iy;  f[2]  = iz;
    f[3]  = sx;  f[4]  = sy;  f[5]  = sz;
    f[6]  = mex; f[7]  = mey; f[8]  = mez;
    f[9]  = sqrtf(vax); f[10] = sqrtf(vay); f[11] = sqrtf(vaz);
    f[12] = mnx; f[13] = mny; f[14] = mnz;
    f[15] = mxx; f[16] = mxy; f[17] = mxz;
}

// K_C: 32 rows x 1024 cols per block (256 threads, 4 cols/thread).
// Coalesced transposed weights; feats tile in LDS; float4 x; NT stores.
__global__ __launch_bounds__(256) void kC_out(
    const float* __restrict__ x, const float* __restrict__ feats,
    const float* __restrict__ wsT, const float* __restrict__ b_out,
    const float* __restrict__ strength, float* __restrict__ out) {
    __shared__ float f_lds[32 * 18];
    const int tid = threadIdx.x;
    const int row0 = blockIdx.x * 32;
    const int c0 = blockIdx.y * 1024 + tid * 4;

    {
        const float* src = feats + (size_t)row0 * 18;
        f_lds[tid] = src[tid];
        f_lds[tid + 256] = src[tid + 256];
        if (tid < 64) f_lds[tid + 512] = src[tid + 512];
    }

    floatx4 wk[18];
#pragma unroll
    for (int k = 0; k < 18; ++k) {
        wk[k] = *reinterpret_cast<const floatx4*>(wsT + (size_t)k * DD + c0);
    }
    const floatx4 bo = *reinterpret_cast<const floatx4*>(b_out + c0);
    const float sabs = fabsf(strength[0]);
    __syncthreads();

#pragma unroll 1
    for (int r = 0; r < 32; r += 2) {
        const int rowA = row0 + r, rowB = row0 + r + 1;
        const float* fA = f_lds + r * 18;
        const float* fB = f_lds + (r + 1) * 18;
        const floatx4 xA = *reinterpret_cast<const floatx4*>(x + (size_t)rowA * DD + c0);
        const floatx4 xB = *reinterpret_cast<const floatx4*>(x + (size_t)rowB * DD + c0);
        floatx4 pA = bo, pB = bo;
#pragma unroll
        for (int k = 0; k < 18; ++k) {
            pA += fA[k] * wk[k];
            pB += fB[k] * wk[k];
        }
        floatx4 oA, oB;
        oA.x = xA.x + fast_tanh(pA.x) * sabs;
        oA.y = xA.y + fast_tanh(pA.y) * sabs;
        oA.z = xA.z + fast_tanh(pA.z) * sabs;
        oA.w = xA.w + fast_tanh(pA.w) * sabs;
        oB.x = xB.x + fast_tanh(pB.x) * sabs;
        oB.y = xB.y + fast_tanh(pB.y) * sabs;
        oB.z = xB.z + fast_tanh(pB.z) * sabs;
        oB.w = xB.w + fast_tanh(pB.w) * sabs;
        __builtin_nontemporal_store(oA, reinterpret_cast<floatx4*>(out + (size_t)rowA * DD + c0));
        __builtin_nontemporal_store(oB, reinterpret_cast<floatx4*>(out + (size_t)rowB * DD + c0));
    }
}

extern "C" void kernel_launch(void* const* d_in, const int* in_sizes, int n_in,
                              void* d_out, int out_size, void* d_ws, size_t ws_size,
                              hipStream_t stream) {
    const float* x        = (const float*)d_in[0];
    const float* lorenz   = (const float*)d_in[1];
    const float* strength = (const float*)d_in[2];
    const float* W_in     = (const float*)d_in[3];
    const float* b_in     = (const float*)d_in[4];
    const float* W_out    = (const float*)d_in[5];
    const float* b_out    = (const float*)d_in[6];
    float* out = (float*)d_out;

    const int N = in_sizes[0] / DD;  // 16384
    float* state0 = (float*)d_ws;            // N*3 floats
    float* feats  = state0 + (size_t)N * 3;  // N*18 floats
    float* wsT    = feats + (size_t)N * 18;  // 18*2048 floats

    kA_state0<<<N / 4, 256, 0, stream>>>(x, W_in, b_in, state0, W_out, wsT);
    kB_integrate<<<N / 256, 256, 0, stream>>>(state0, lorenz, feats);
    dim3 g3(N / 32, DD / 1024);
    kC_out<<<g3, 256, 0, stream>>>(x, feats, wsT, b_out, strength, out);
}